// Round 18
// baseline (296.225 us; speedup 1.0000x reference)
//
#include <hip/hip_runtime.h>
#include <hip/hip_bf16.h>
#include <stdint.h>

#define D_ 2048
#define E_ 128
#define H_ 16
#define NB_ 2
#define NSEQ_ 2048
#define NTOK_ 4096
#define NCH_ 32

typedef short bf16s;
typedef __attribute__((ext_vector_type(8))) short bf16x8;
typedef __attribute__((ext_vector_type(4))) float f32x4;

__device__ __forceinline__ short f2b(float f) {
  __hip_bfloat16 h = __float2bfloat16(f);
  return *reinterpret_cast<short*>(&h);
}
__device__ __forceinline__ float b2f(short s) {
  __hip_bfloat16 h;
  *reinterpret_cast<short*>(&h) = s;
  return __bfloat162float(h);
}

__device__ __forceinline__ void gload_lds16(const void* g, void* l) {
  __builtin_amdgcn_global_load_lds(
      (__attribute__((address_space(1))) void*)(const_cast<void*>(g)),
      (__attribute__((address_space(3))) void*)(l), 16, 0, 0);
}

template <int N>
__device__ __forceinline__ void wait_vmcnt() {
  if constexpr (N == 0)       asm volatile("s_waitcnt vmcnt(0)" ::: "memory");
  else if constexpr (N == 3)  asm volatile("s_waitcnt vmcnt(3)" ::: "memory");
  else if constexpr (N == 5)  asm volatile("s_waitcnt vmcnt(5)" ::: "memory");
  else if constexpr (N == 6)  asm volatile("s_waitcnt vmcnt(6)" ::: "memory");
  else static_assert(N == 0, "unsupported vmcnt");
}
__device__ __forceinline__ void lgkm0_fence() {
  asm volatile("s_waitcnt lgkmcnt(0)" ::: "memory");
  __builtin_amdgcn_sched_barrier(0);
}

// ---------------- elementwise convert x -> bf16 ----------------
__global__ __launch_bounds__(256)
void cvt_bf16(const float* __restrict__ x, bf16s* __restrict__ y) {
  const size_t i = (size_t)blockIdx.x * 256 + threadIdx.x;
  const float4 a = ((const float4*)x)[i * 2];
  const float4 b = ((const float4*)x)[i * 2 + 1];
  bf16x8 o;
  o[0] = f2b(a.x); o[1] = f2b(a.y); o[2] = f2b(a.z); o[3] = f2b(a.w);
  o[4] = f2b(b.x); o[5] = f2b(b.y); o[6] = f2b(b.z); o[7] = f2b(b.w);
  *(bf16x8*)&y[i * 8] = o;
}

// -------- transpose weights f32[K][N] -> bf16[N][K]; z==3 folds norm_w -----
__global__ __launch_bounds__(256)
void transpose_w(const float* __restrict__ Wq, const float* __restrict__ Wk,
                 const float* __restrict__ Wv, const float* __restrict__ Wo,
                 const float* __restrict__ nw, bf16s* __restrict__ WqT,
                 bf16s* __restrict__ WkT, bf16s* __restrict__ WvT,
                 bf16s* __restrict__ WoT) {
  const float* src; bf16s* dst;
  if (blockIdx.z == 0)      { src = Wq; dst = WqT; }
  else if (blockIdx.z == 1) { src = Wk; dst = WkT; }
  else if (blockIdx.z == 2) { src = Wv; dst = WvT; }
  else                      { src = Wo; dst = WoT; }
  __shared__ float tile[64][65];
  const int n0 = blockIdx.x * 64, k0 = blockIdx.y * 64;
  const int t = threadIdx.x;
  const int tr = t >> 6, tc = t & 63;
#pragma unroll
  for (int rr = 0; rr < 16; ++rr) {
    const int row = rr * 4 + tr;
    tile[row][tc] = src[(size_t)(k0 + row) * D_ + n0 + tc];
  }
  __syncthreads();
  const float wk = (blockIdx.z == 3) ? nw[k0 + tc] : 1.f;
#pragma unroll
  for (int rr = 0; rr < 16; ++rr) {
    const int row = rr * 4 + tr;
    dst[(size_t)(n0 + row) * D_ + k0 + tc] = f2b(tile[tc][row] * wk);
  }
}

// ---------------- ld = log_sigmoid(x @ Wf), f32 ----------------
__global__ __launch_bounds__(256)
void ld_gemm(const float* __restrict__ x, const float* __restrict__ Wf,
             float* __restrict__ ldb) {
  const int t = threadIdx.x;
  const int col = t & 15;
  const int tok = blockIdx.x * 16 + (t >> 4);
  const float4* xr = (const float4*)(x + (size_t)tok * D_);
  float s = 0.f;
#pragma unroll 4
  for (int kk = 0; kk < D_ / 4; ++kk) {
    const float4 xv = xr[kk];
    const int k4 = kk * 4;
    s += xv.x * Wf[(k4 + 0) * H_ + col];
    s += xv.y * Wf[(k4 + 1) * H_ + col];
    s += xv.z * Wf[(k4 + 2) * H_ + col];
    s += xv.w * Wf[(k4 + 3) * H_ + col];
  }
  const float m = fminf(s, 0.f);
  ldb[(size_t)tok * H_ + col] = m - log1pf(__expf(-fabsf(s)));
}

// ======== fused-z qkv GEMM: BM=256, BN=128, BK=32, 256 blocks ==============
// 2 LDS slots (80 KB exactly) -> 2 blocks/CU; stage AFTER end-of-tile
// barrier (slot legality), counted vmcnt(5). 48 MFMA per barrier-pair.
__global__ __launch_bounds__(512, 2)
void gemm_qkv_fz(const bf16s* __restrict__ xb, const bf16s* __restrict__ WqT,
                 const bf16s* __restrict__ WkT, const bf16s* __restrict__ WvT,
                 bf16s* __restrict__ qb, bf16s* __restrict__ kb,
                 bf16s* __restrict__ vb) {
  const int bn = blockIdx.x & 15, bm = blockIdx.x >> 4;
  __shared__ bf16s As[2 * 256 * 32];        // [slot][256][32]  32 KB
  __shared__ bf16s Bs[2 * 3 * 128 * 32];    // [slot][z][128][32]  48 KB
  const int t = threadIdx.x;
  const int w = t >> 6, l = t & 63;
  const int wm = w >> 1, wn = w & 1;        // 4 x 2 wave grid
  const int lr = l & 15, lk = l >> 4;
  const int srow = t >> 2;                  // staging row 0..127
  const int scs = (t & 3) ^ ((srow >> 1) & 3);  // pre-swizzled source chunk

  const size_t abase = (size_t)(bm * 256) * D_;
  const size_t bbase = (size_t)(bn * 128) * D_;

  f32x4 acc[3][4][4] = {};

  auto stage = [&](int m) {
    const int slot = m & 1;
    const int k0 = m * 32;
    gload_lds16(&xb[abase + (size_t)srow * D_ + k0 + scs * 8],
                &As[slot * 8192 + w * 512]);
    gload_lds16(&xb[abase + (size_t)(128 + srow) * D_ + k0 + scs * 8],
                &As[slot * 8192 + 4096 + w * 512]);
    gload_lds16(&WqT[bbase + (size_t)srow * D_ + k0 + scs * 8],
                &Bs[slot * 12288 + w * 512]);
    gload_lds16(&WkT[bbase + (size_t)srow * D_ + k0 + scs * 8],
                &Bs[slot * 12288 + 4096 + w * 512]);
    gload_lds16(&WvT[bbase + (size_t)srow * D_ + k0 + scs * 8],
                &Bs[slot * 12288 + 8192 + w * 512]);
  };
  auto ldA = [&](int slot, int fm) -> bf16x8 {
    const int row = wm * 64 + fm * 16 + lr;
    return *(const bf16x8*)&As[slot * 8192 + row * 32 +
                               (lk ^ ((row >> 1) & 3)) * 8];
  };
  auto ldB = [&](int slot, int z, int fn) -> bf16x8 {
    const int row = wn * 64 + fn * 16 + lr;
    return *(const bf16x8*)&Bs[slot * 12288 + z * 4096 + row * 32 +
                               (lk ^ ((row >> 1) & 3)) * 8];
  };

  // prologue: stage tiles 0,1 (10 loads); drain tile 0
  stage(0); stage(1);
  wait_vmcnt<5>();
  __builtin_amdgcn_s_barrier();

  for (int j = 0; j < 64; ++j) {
    const int slot = j & 1;
    bf16x8 af[4], bfr[4];
    // phase 0: z=0 (q)
#pragma unroll
    for (int fm = 0; fm < 4; ++fm) af[fm] = ldA(slot, fm);
#pragma unroll
    for (int fn = 0; fn < 4; ++fn) bfr[fn] = ldB(slot, 0, fn);
    lgkm0_fence();
    __builtin_amdgcn_s_setprio(1);
#pragma unroll
    for (int fm = 0; fm < 4; ++fm)
#pragma unroll
      for (int fn = 0; fn < 4; ++fn)
        acc[0][fm][fn] = __builtin_amdgcn_mfma_f32_16x16x32_bf16(
            af[fm], bfr[fn], acc[0][fm][fn], 0, 0, 0);
    __builtin_amdgcn_s_setprio(0);
    // phase 1: z=1 (k)
#pragma unroll
    for (int fn = 0; fn < 4; ++fn) bfr[fn] = ldB(slot, 1, fn);
    lgkm0_fence();
    __builtin_amdgcn_s_setprio(1);
#pragma unroll
    for (int fm = 0; fm < 4; ++fm)
#pragma unroll
      for (int fn = 0; fn < 4; ++fn)
        acc[1][fm][fn] = __builtin_amdgcn_mfma_f32_16x16x32_bf16(
            af[fm], bfr[fn], acc[1][fm][fn], 0, 0, 0);
    __builtin_amdgcn_s_setprio(0);
    // phase 2: z=2 (v)
#pragma unroll
    for (int fn = 0; fn < 4; ++fn) bfr[fn] = ldB(slot, 2, fn);
    lgkm0_fence();
    __builtin_amdgcn_s_setprio(1);
#pragma unroll
    for (int fm = 0; fm < 4; ++fm)
#pragma unroll
      for (int fn = 0; fn < 4; ++fn)
        acc[2][fm][fn] = __builtin_amdgcn_mfma_f32_16x16x32_bf16(
            af[fm], bfr[fn], acc[2][fm][fn], 0, 0, 0);
    __builtin_amdgcn_s_setprio(0);
    // all reads of tile j done (per-wave lgkm0 above) -> barrier, then
    // re-stage slot (j&1) with tile j+2; counted drain for tile j+1.
    __builtin_amdgcn_s_barrier();
    if (j <= 61) {
      stage(j + 2);
      wait_vmcnt<5>();
      __builtin_amdgcn_s_barrier();
    } else if (j == 62) {
      wait_vmcnt<0>();
      __builtin_amdgcn_s_barrier();
    }
  }

  // epilogue: 3 outputs; silu for z=0,1
#pragma unroll
  for (int z = 0; z < 3; ++z) {
    bf16s* outp = (z == 0) ? qb : (z == 1) ? kb : vb;
#pragma unroll
    for (int fm = 0; fm < 4; ++fm) {
      const int row = bm * 256 + wm * 64 + fm * 16 + lk * 4;
#pragma unroll
      for (int fn = 0; fn < 4; ++fn) {
        const int col = bn * 128 + wn * 64 + fn * 16 + lr;
#pragma unroll
        for (int r = 0; r < 4; ++r) {
          float vv = acc[z][fm][fn][r];
          if (z < 2) vv = vv / (1.f + __expf(-vv));  // silu
          outp[(size_t)(row + r) * D_ + col] = f2b(vv);
        }
      }
    }
  }
}

// ======== gemm_out, fz pipeline: BM=256, BN=128, BK=32, 256 blocks =========
__global__ __launch_bounds__(512, 2)
void gemm_out_fz(const bf16s* __restrict__ A, const bf16s* __restrict__ Bt,
                 const float* __restrict__ rs, float* __restrict__ out) {
  const int bn = blockIdx.x & 15, bm = blockIdx.x >> 4;
  __shared__ bf16s As[3 * 256 * 32];   // 48 KB
  __shared__ bf16s Bs[3 * 128 * 32];   // 24 KB
  const int t = threadIdx.x;
  const int w = t >> 6, l = t & 63;
  const int wm = w >> 1, wn = w & 1;
  const int lr = l & 15, lk = l >> 4;
  const int srow = t >> 2;
  const int scs = (t & 3) ^ ((srow >> 1) & 3);

  const size_t abase = (size_t)(bm * 256) * D_;
  const size_t bbase = (size_t)(bn * 128) * D_;

  f32x4 acc[4][4] = {};

  auto stageA = [&](int m, int slot, int p) {
    gload_lds16(&A[abase + (size_t)(p * 128 + srow) * D_ + m * 32 + scs * 8],
                &As[slot * 8192 + p * 4096 + w * 512]);
  };
  auto stageB = [&](int m, int slot) {
    gload_lds16(&Bt[bbase + (size_t)srow * D_ + m * 32 + scs * 8],
                &Bs[slot * 4096 + w * 512]);
  };
  auto ldA = [&](int slot, int fm) -> bf16x8 {
    const int row = wm * 64 + fm * 16 + lr;
    return *(const bf16x8*)&As[slot * 8192 + row * 32 +
                               (lk ^ ((row >> 1) & 3)) * 8];
  };
  auto ldB = [&](int slot, int fn) -> bf16x8 {
    const int row = wn * 64 + fn * 16 + lr;
    return *(const bf16x8*)&Bs[slot * 4096 + row * 32 +
                               (lk ^ ((row >> 1) & 3)) * 8];
  };

#pragma unroll
  for (int m = 0; m < 3; ++m) { stageA(m, m, 0); stageA(m, m, 1); stageB(m, m); }
  wait_vmcnt<6>();  // tile 0 landed
  __builtin_amdgcn_s_barrier();

  int slot = 0, slot2 = 2;
  for (int j = 0; j < 64; ++j) {
    bf16x8 af[4], bfr[4];
#pragma unroll
    for (int fm = 0; fm < 4; ++fm) af[fm] = ldA(slot, fm);
#pragma unroll
    for (int fn = 0; fn < 4; ++fn) bfr[fn] = ldB(slot, fn);
    if (j <= 61) { stageA(j + 2, slot2, 0); stageA(j + 2, slot2, 1);
                   stageB(j + 2, slot2); }
    lgkm0_fence();
    __builtin_amdgcn_s_setprio(1);
#pragma unroll
    for (int fm = 0; fm < 4; ++fm)
#pragma unroll
      for (int fn = 0; fn < 4; ++fn)
        acc[fm][fn] = __builtin_amdgcn_mfma_f32_16x16x32_bf16(
            af[fm], bfr[fn], acc[fm][fn], 0, 0, 0);
    __builtin_amdgcn_s_setprio(0);
    if (j <= 61)      wait_vmcnt<3>();
    else if (j == 62) wait_vmcnt<0>();
    __builtin_amdgcn_s_barrier();
    slot = (slot == 2) ? 0 : slot + 1;
    slot2 = (slot2 == 2) ? 0 : slot2 + 1;
  }

#pragma unroll
  for (int fm = 0; fm < 4; ++fm) {
    const int row = bm * 256 + wm * 64 + fm * 16 + lk * 4;
#pragma unroll
    for (int fn = 0; fn < 4; ++fn) {
      const int col = bn * 128 + wn * 64 + fn * 16 + lr;
#pragma unroll
      for (int r = 0; r < 4; ++r)
        out[(size_t)(row + r) * D_ + col] = acc[fm][fn][r] * rs[row + r];
    }
  }
}

// ============ chunked linear attention, 3-pass parallel decomposition =======
__global__ __launch_bounds__(256)
void chunk_state(const bf16s* __restrict__ k, const bf16s* __restrict__ v,
                 const float* __restrict__ ldp, bf16s* __restrict__ Mbuf,
                 float* __restrict__ totb) {
  const int c = blockIdx.x, bh = blockIdx.y;
  const int b = bh >> 4, h = bh & 15;
  const int t = threadIdx.x;
  const int w = t >> 6, l = t & 63;
  const int lr = l & 15, lk = l >> 4;

  __shared__ bf16s Kt[64 * 128];
  __shared__ bf16s Vn[64 * 128];
  __shared__ bf16s KdT[128 * 64];
  __shared__ bf16s VtT[128 * 64];
  __shared__ float cumS[64];
  char* cKt = (char*)Kt; char* cVn = (char*)Vn;
  char* cKdT = (char*)KdT; char* cVtT = (char*)VtT;

  const size_t grow0 = (size_t)b * NSEQ_ + c * 64;
#pragma unroll
  for (int j = 0; j < 4; ++j) {
    const int lrow = w * 16 + j * 4 + (l >> 4);
    const int ck = (l & 15) ^ (lrow & 7);
    const size_t goff = (grow0 + lrow) * D_ + h * E_ + ck * 8;
    const int lbase = (w * 16 + j * 4) * 128;
    gload_lds16(&k[goff], &Kt[lbase]);
    gload_lds16(&v[goff], &Vn[lbase]);
  }
  if (w == 0) {
    float val = ldp[(grow0 + l) * H_ + h];
#pragma unroll
    for (int off = 1; off < 64; off <<= 1) {
      float pv = __shfl_up(val, off);
      if (l >= off) val += pv;
    }
    cumS[l] = val;
  }
  __syncthreads();
  const float tot = cumS[63];
  if (t == 0) totb[bh * NCH_ + c] = tot;

#pragma unroll
  for (int it = 0; it < 4; ++it) {
    const int task = t + it * 256;
    const int i = task >> 4, cx = task & 15;
    const int sb = i * 256 + ((cx * 16) ^ ((i & 7) << 4));
    bf16x8 vv = *(const bf16x8*)(cVn + sb);
    bf16x8 kk8 = *(const bf16x8*)(cKt + sb);
    const float sE = __expf(tot - cumS[i]);
#pragma unroll
    for (int jj = 0; jj < 8; ++jj) {
      const int e = cx * 8 + jj;
      const int db = e * 128 + ((i * 2) ^ ((e & 7) << 4));
      *(bf16s*)(cVtT + db) = vv[jj];
      *(bf16s*)(cKdT + db) = f2b(b2f(kk8[jj]) * sE);
    }
  }
  __syncthreads();

  const int wm = w >> 1, wn = w & 1;
  f32x4 acc[4][4] = {};
#pragma unroll
  for (int kk2 = 0; kk2 < 2; ++kk2) {
    const int cb = (kk2 * 32 + lk * 8) * 2;
    bf16x8 af[4], bfr[4];
#pragma unroll
    for (int tm = 0; tm < 4; ++tm) {
      const int fr = wm * 64 + tm * 16 + lr;
      af[tm] = *(const bf16x8*)(cVtT + fr * 128 + (cb ^ ((fr & 7) << 4)));
    }
#pragma unroll
    for (int tn = 0; tn < 4; ++tn) {
      const int er = wn * 64 + tn * 16 + lr;
      bfr[tn] = *(const bf16x8*)(cKdT + er * 128 + (cb ^ ((er & 7) << 4)));
    }
#pragma unroll
    for (int tm = 0; tm < 4; ++tm)
#pragma unroll
      for (int tn = 0; tn < 4; ++tn)
        acc[tm][tn] = __builtin_amdgcn_mfma_f32_16x16x32_bf16(
            af[tm], bfr[tn], acc[tm][tn], 0, 0, 0);
  }
  const size_t mb = (size_t)(bh * NCH_ + c) * 128 * 128;
#pragma unroll
  for (int tm = 0; tm < 4; ++tm) {
#pragma unroll
    for (int tn = 0; tn < 4; ++tn) {
#pragma unroll
      for (int r = 0; r < 4; ++r) {
        const int f = wm * 64 + tm * 16 + lk * 4 + r;
        const int e = wn * 64 + tn * 16 + lr;
        Mbuf[mb + f * 128 + e] = f2b(acc[tm][tn][r]);
      }
    }
  }
}

__global__ __launch_bounds__(256)
void state_scan(const bf16s* __restrict__ Mbuf, const float* __restrict__ totb,
                bf16s* __restrict__ Sbuf) {
  const int sl = blockIdx.x;
  const int bh = blockIdx.y;
  const int t = threadIdx.x;
  const int fr = sl * 16 + (t >> 4);
  const int e0 = (t & 15) * 8;
  const size_t base = ((size_t)(bh * NCH_) * 128 + fr) * 128 + e0;
  const size_t cstride = 128 * 128;
  __shared__ float tots[NCH_];
  if (t < NCH_) tots[t] = totb[bh * NCH_ + t];
  __syncthreads();
  float acc[8] = {};
  bf16x8 m0 = *(const bf16x8*)&Mbuf[base + 0 * cstride];
  bf16x8 m1 = *(const bf16x8*)&Mbuf[base + 1 * cstride];
  bf16x8 m2 = *(const bf16x8*)&Mbuf[base + 2 * cstride];
  bf16x8 m3 = *(const bf16x8*)&Mbuf[base + 3 * cstride];
#pragma unroll
  for (int c = 0; c < NCH_; ++c) {
    bf16x8 sv;
#pragma unroll
    for (int j = 0; j < 8; ++j) sv[j] = f2b(acc[j]);
    *(bf16x8*)&Sbuf[base + (size_t)c * cstride] = sv;
    const bf16x8 mc = ((c & 3) == 0) ? m0 : ((c & 3) == 1) ? m1
                     : ((c & 3) == 2) ? m2 : m3;
    const float dt = __expf(tots[c]);
#pragma unroll
    for (int j = 0; j < 8; ++j) acc[j] = acc[j] * dt + b2f(mc[j]);
    if (c + 4 < NCH_) {
      const bf16x8 mn = *(const bf16x8*)&Mbuf[base + (size_t)(c + 4) * cstride];
      if ((c & 3) == 0) m0 = mn;
      else if ((c & 3) == 1) m1 = mn;
      else if ((c & 3) == 2) m2 = mn;
      else m3 = mn;
    }
  }
}

__global__ __launch_bounds__(256)
void attn_out(const bf16s* __restrict__ q, const bf16s* __restrict__ k,
              const bf16s* __restrict__ v, const float* __restrict__ ldp,
              const bf16s* __restrict__ Sbuf, bf16s* __restrict__ o) {
  const int c = blockIdx.x, bh = blockIdx.y;
  const int b = bh >> 4, h = bh & 15;
  const int t = threadIdx.x;
  const int w = t >> 6, l = t & 63;
  const int lr = l & 15, lk = l >> 4;

  __shared__ bf16s Qt[64 * 128];
  __shared__ bf16s Kt[64 * 128];
  __shared__ bf16s Vn[64 * 128];
  __shared__ bf16s VtT[128 * 64];
  __shared__ bf16s Pm[64 * 64];
  __shared__ float cumS[64];
  char* cQt = (char*)Qt; char* cKt = (char*)Kt; char* cVn = (char*)Vn;
  char* cVtT = (char*)VtT; char* cPm = (char*)Pm;

  const size_t grow0 = (size_t)b * NSEQ_ + c * 64;
  const size_t sbase = (size_t)(bh * NCH_ + c) * 128 * 128;
  const bf16x8* Sp = (const bf16x8*)&Sbuf[sbase];
#pragma unroll
  for (int j = 0; j < 4; ++j) {
    const int lrow = w * 16 + j * 4 + (l >> 4);
    const int ck = (l & 15) ^ (lrow & 7);
    const size_t goff = (grow0 + lrow) * D_ + h * E_ + ck * 8;
    const int lbase = (w * 16 + j * 4) * 128;
    gload_lds16(&q[goff], &Qt[lbase]);
    gload_lds16(&k[goff], &Kt[lbase]);
    gload_lds16(&v[goff], &Vn[lbase]);
  }
  if (w == 0) {
    float val = ldp[(grow0 + l) * H_ + h];
#pragma unroll
    for (int off = 1; off < 64; off <<= 1) {
      float pv = __shfl_up(val, off);
      if (l >= off) val += pv;
    }
    cumS[l] = val;
  }
  __syncthreads();

#pragma unroll
  for (int it = 0; it < 4; ++it) {
    const int task = t + it * 256;
    const int i = task >> 4, cx = task & 15;
    const int sb = i * 256 + ((cx * 16) ^ ((i & 7) << 4));
    bf16x8 vv = *(const bf16x8*)(cVn + sb);
#pragma unroll
    for (int jj = 0; jj < 8; ++jj) {
      const int e = cx * 8 + jj;
      const int db = e * 128 + ((i * 2) ^ ((e & 7) << 4));
      *(bf16s*)(cVtT + db) = vv[jj];
    }
  }

  f32x4 accs[4] = {};
  f32x4 acco[8] = {};
#pragma unroll
  for (int kk = 0; kk < 4; ++kk) {
    const int cb = (kk * 32 + lk * 8) * 2;
    const int ar = w * 16 + lr;
    bf16x8 aq = *(const bf16x8*)(cQt + ar * 256 + (cb ^ ((ar & 7) << 4)));
#pragma unroll
    for (int tn = 0; tn < 4; ++tn) {
      const int br = tn * 16 + lr;
      bf16x8 bk = *(const bf16x8*)(cKt + br * 256 + (cb ^ ((br & 7) << 4)));
      accs[tn] = __builtin_amdgcn_mfma_f32_16x16x32_bf16(aq, bk, accs[tn], 0, 0, 0);
    }
#pragma unroll
    for (int tf = 0; tf < 8; ++tf) {
      bf16x8 bs = Sp[(tf * 16 + lr) * 16 + kk * 4 + lk];
      acco[tf] = __builtin_amdgcn_mfma_f32_16x16x32_bf16(aq, bs, acco[tf], 0, 0, 0);
    }
  }
#pragma unroll
  for (int r = 0; r < 4; ++r) {
    const float gI = __expf(cumS[w * 16 + lk * 4 + r]);
#pragma unroll
    for (int tf = 0; tf < 8; ++tf) acco[tf][r] *= gI;
  }
#pragma unroll
  for (int tn = 0; tn < 4; ++tn) {
    const int j = tn * 16 + lr;
    const float cj = cumS[j];
#pragma unroll
    for (int r = 0; r < 4; ++r) {
      const int i = w * 16 + lk * 4 + r;
      const float sv = (j <= i) ? accs[tn][r] * __expf(cumS[i] - cj) : 0.f;
      *(bf16s*)(cPm + i * 128 + ((j * 2) ^ ((i & 7) << 4))) = f2b(sv);
    }
  }
  __syncthreads();

#pragma unroll
  for (int kk2 = 0; kk2 < 2; ++kk2) {
    const int cb = (kk2 * 32 + lk * 8) * 2;
    const int pr = w * 16 + lr;
    bf16x8 ap = *(const bf16x8*)(cPm + pr * 128 + (cb ^ ((pr & 7) << 4)));
#pragma unroll
    for (int tf = 0; tf < 8; ++tf) {
      const int fr = tf * 16 + lr;
      bf16x8 bv = *(const bf16x8*)(cVtT + fr * 128 + (cb ^ ((fr & 7) << 4)));
      acco[tf] = __builtin_amdgcn_mfma_f32_16x16x32_bf16(ap, bv, acco[tf], 0, 0, 0);
    }
  }
#pragma unroll
  for (int tf = 0; tf < 8; ++tf) {
#pragma unroll
    for (int r = 0; r < 4; ++r) {
      const int i = w * 16 + lk * 4 + r;
      o[(grow0 + i) * D_ + h * E_ + tf * 16 + lr] = f2b(acco[tf][r]);
    }
  }
}

// -------- RMS scale only: s[tok] = rsqrt(mean(o^2)+eps) --------------------
__global__ __launch_bounds__(256)
void rms_scale(const bf16s* __restrict__ o, float* __restrict__ sout) {
  const int tok = blockIdx.x;
  const int t = threadIdx.x;
  bf16x8 vv = *(const bf16x8*)&o[(size_t)tok * D_ + t * 8];
  float s = 0.f;
#pragma unroll
  for (int j = 0; j < 8; ++j) { const float f = b2f(vv[j]); s += f * f; }
#pragma unroll
  for (int off2 = 32; off2 > 0; off2 >>= 1) s += __shfl_down(s, off2);
  __shared__ float wsum[4];
  if ((t & 63) == 0) wsum[t >> 6] = s;
  __syncthreads();
  if (t == 0)
    sout[tok] = rsqrtf((wsum[0] + wsum[1] + wsum[2] + wsum[3]) * (1.f / D_) +
                       1e-6f);
}

extern "C" void kernel_launch(void* const* d_in, const int* in_sizes, int n_in,
                              void* d_out, int out_size, void* d_ws,
                              size_t ws_size, hipStream_t stream) {
  (void)in_sizes; (void)n_in; (void)out_size;
  const float* x  = (const float*)d_in[0];
  const float* Wq = (const float*)d_in[1];
  const float* Wk = (const float*)d_in[2];
  const float* Wv = (const float*)d_in[3];
  const float* Wf = (const float*)d_in[4];
  const float* Wo = (const float*)d_in[5];
  const float* nw = (const float*)d_in[6];
  float* out = (float*)d_out;

  char* ws = (char*)d_ws;
  const size_t MB = 1024 * 1024;
  bf16s* xb   = (bf16s*)(ws + 0);
  bf16s* WqT  = (bf16s*)(ws + 16 * MB);
  bf16s* WkT  = (bf16s*)(ws + 24 * MB);
  bf16s* WvT  = (bf16s*)(ws + 32 * MB);
  bf16s* Sbuf = (bf16s*)(ws + 0);        // alias: live after gemm_qkv
  float* totb = (float*)(ws + 32 * MB);  // alias: live after gemm_qkv
  bf16s* WoT  = (bf16s*)(ws + 40 * MB);
  bf16s* qb   = (bf16s*)(ws + 48 * MB);
  bf16s* kb   = (bf16s*)(ws + 64 * MB);
  bf16s* vb   = (bf16s*)(ws + 80 * MB);
  bf16s* ob   = (bf16s*)(ws + 96 * MB);
  bf16s* Mbuf = (bf16s*)(ws + 112 * MB);
  float* ldb  = (float*)(ws + 144 * MB);
  float* rsb  = (float*)(ws + 145 * MB);
  if (146 * MB > ws_size) return;

  cvt_bf16<<<NTOK_ * D_ / 8 / 256, 256, 0, stream>>>(x, xb);
  transpose_w<<<dim3(32, 32, 4), 256, 0, stream>>>(Wq, Wk, Wv, Wo, nw, WqT,
                                                   WkT, WvT, WoT);
  ld_gemm<<<NTOK_ / 16, 256, 0, stream>>>(x, Wf, ldb);
  gemm_qkv_fz<<<256, 512, 0, stream>>>(xb, WqT, WkT, WvT, qb, kb, vb);
  chunk_state<<<dim3(NCH_, NB_ * H_), 256, 0, stream>>>(kb, vb, ldb, Mbuf, totb);
  state_scan<<<dim3(8, NB_ * H_), 256, 0, stream>>>(Mbuf, totb, Sbuf);
  attn_out<<<dim3(NCH_, NB_ * H_), 256, 0, stream>>>(qb, kb, vb, ldb, Sbuf, ob);
  rms_scale<<<NTOK_, 256, 0, stream>>>(ob, rsb);
  gemm_out_fz<<<256, 512, 0, stream>>>(ob, WoT, rsb, out);
}

// Round 19
// 275.365 us; speedup vs baseline: 1.0758x; 1.0758x over previous
//
#include <hip/hip_runtime.h>
#include <hip/hip_bf16.h>
#include <stdint.h>

#define D_ 2048
#define E_ 128
#define H_ 16
#define NB_ 2
#define NSEQ_ 2048
#define NTOK_ 4096
#define NCH_ 32

typedef short bf16s;
typedef __attribute__((ext_vector_type(8))) short bf16x8;
typedef __attribute__((ext_vector_type(4))) float f32x4;

__device__ __forceinline__ short f2b(float f) {
  __hip_bfloat16 h = __float2bfloat16(f);
  return *reinterpret_cast<short*>(&h);
}
__device__ __forceinline__ float b2f(short s) {
  __hip_bfloat16 h;
  *reinterpret_cast<short*>(&h) = s;
  return __bfloat162float(h);
}

__device__ __forceinline__ void gload_lds16(const void* g, void* l) {
  __builtin_amdgcn_global_load_lds(
      (__attribute__((address_space(1))) void*)(const_cast<void*>(g)),
      (__attribute__((address_space(3))) void*)(l), 16, 0, 0);
}

template <int N>
__device__ __forceinline__ void wait_vmcnt() {
  if constexpr (N == 0)       asm volatile("s_waitcnt vmcnt(0)" ::: "memory");
  else if constexpr (N == 3)  asm volatile("s_waitcnt vmcnt(3)" ::: "memory");
  else if constexpr (N == 5)  asm volatile("s_waitcnt vmcnt(5)" ::: "memory");
  else if constexpr (N == 6)  asm volatile("s_waitcnt vmcnt(6)" ::: "memory");
  else if constexpr (N == 10) asm volatile("s_waitcnt vmcnt(10)" ::: "memory");
  else static_assert(N == 0, "unsupported vmcnt");
}
__device__ __forceinline__ void lgkm0_fence() {
  asm volatile("s_waitcnt lgkmcnt(0)" ::: "memory");
  __builtin_amdgcn_sched_barrier(0);
}

// ---------------- elementwise convert x -> bf16 ----------------
__global__ __launch_bounds__(256)
void cvt_bf16(const float* __restrict__ x, bf16s* __restrict__ y) {
  const size_t i = (size_t)blockIdx.x * 256 + threadIdx.x;
  const float4 a = ((const float4*)x)[i * 2];
  const float4 b = ((const float4*)x)[i * 2 + 1];
  bf16x8 o;
  o[0] = f2b(a.x); o[1] = f2b(a.y); o[2] = f2b(a.z); o[3] = f2b(a.w);
  o[4] = f2b(b.x); o[5] = f2b(b.y); o[6] = f2b(b.z); o[7] = f2b(b.w);
  *(bf16x8*)&y[i * 8] = o;
}

// -------- transpose weights f32[K][N] -> bf16[N][K]; z==3 folds norm_w -----
__global__ __launch_bounds__(256)
void transpose_w(const float* __restrict__ Wq, const float* __restrict__ Wk,
                 const float* __restrict__ Wv, const float* __restrict__ Wo,
                 const float* __restrict__ nw, bf16s* __restrict__ WqT,
                 bf16s* __restrict__ WkT, bf16s* __restrict__ WvT,
                 bf16s* __restrict__ WoT) {
  const float* src; bf16s* dst;
  if (blockIdx.z == 0)      { src = Wq; dst = WqT; }
  else if (blockIdx.z == 1) { src = Wk; dst = WkT; }
  else if (blockIdx.z == 2) { src = Wv; dst = WvT; }
  else                      { src = Wo; dst = WoT; }
  __shared__ float tile[64][65];
  const int n0 = blockIdx.x * 64, k0 = blockIdx.y * 64;
  const int t = threadIdx.x;
  const int tr = t >> 6, tc = t & 63;
#pragma unroll
  for (int rr = 0; rr < 16; ++rr) {
    const int row = rr * 4 + tr;
    tile[row][tc] = src[(size_t)(k0 + row) * D_ + n0 + tc];
  }
  __syncthreads();
  const float wk = (blockIdx.z == 3) ? nw[k0 + tc] : 1.f;
#pragma unroll
  for (int rr = 0; rr < 16; ++rr) {
    const int row = rr * 4 + tr;
    dst[(size_t)(n0 + row) * D_ + k0 + tc] = f2b(tile[tc][row] * wk);
  }
}

// ---------------- ld = log_sigmoid(x @ Wf), f32 ----------------
__global__ __launch_bounds__(256)
void ld_gemm(const float* __restrict__ x, const float* __restrict__ Wf,
             float* __restrict__ ldb) {
  const int t = threadIdx.x;
  const int col = t & 15;
  const int tok = blockIdx.x * 16 + (t >> 4);
  const float4* xr = (const float4*)(x + (size_t)tok * D_);
  float s = 0.f;
#pragma unroll 4
  for (int kk = 0; kk < D_ / 4; ++kk) {
    const float4 xv = xr[kk];
    const int k4 = kk * 4;
    s += xv.x * Wf[(k4 + 0) * H_ + col];
    s += xv.y * Wf[(k4 + 1) * H_ + col];
    s += xv.z * Wf[(k4 + 2) * H_ + col];
    s += xv.w * Wf[(k4 + 3) * H_ + col];
  }
  const float m = fminf(s, 0.f);
  ldb[(size_t)tok * H_ + col] = m - log1pf(__expf(-fabsf(s)));
}

// ======== fused-z qkv GEMM: BM=256, BN=128, BK=32, 256 blocks (no tail) ====
// 3 LDS slots (120 KB), depth-2 prefetch, counted vmcnt(5), 1 barrier/K-tile.
__global__ __launch_bounds__(512, 2)
void gemm_qkv_fz(const bf16s* __restrict__ xb, const bf16s* __restrict__ WqT,
                 const bf16s* __restrict__ WkT, const bf16s* __restrict__ WvT,
                 bf16s* __restrict__ qb, bf16s* __restrict__ kb,
                 bf16s* __restrict__ vb) {
  const int bn = blockIdx.x & 15, bm = blockIdx.x >> 4;
  __shared__ bf16s As[3 * 256 * 32];        // [slot][256][32]
  __shared__ bf16s Bs[3 * 3 * 128 * 32];    // [slot][z][128][32]
  const int t = threadIdx.x;
  const int w = t >> 6, l = t & 63;
  const int wm = w >> 1, wn = w & 1;        // 4 x 2 wave grid
  const int lr = l & 15, lk = l >> 4;
  const int srow = t >> 2;                  // staging row 0..127
  const int scs = (t & 3) ^ ((srow >> 1) & 3);  // pre-swizzled source chunk

  const size_t abase = (size_t)(bm * 256) * D_;
  const size_t bbase = (size_t)(bn * 128) * D_;

  f32x4 acc[3][4][4] = {};

  auto stageA = [&](int m, int slot, int p) {
    const int k0 = m * 32;
    gload_lds16(&xb[abase + (size_t)(p * 128 + srow) * D_ + k0 + scs * 8],
                &As[slot * 8192 + p * 4096 + w * 512]);
  };
  auto stageB = [&](int m, int slot, int z, const bf16s* Wt) {
    const int k0 = m * 32;
    gload_lds16(&Wt[bbase + (size_t)srow * D_ + k0 + scs * 8],
                &Bs[slot * 12288 + z * 4096 + w * 512]);
  };
  auto ldA = [&](int slot, int fm) -> bf16x8 {
    const int row = wm * 64 + fm * 16 + lr;
    return *(const bf16x8*)&As[slot * 8192 + row * 32 +
                               (lk ^ ((row >> 1) & 3)) * 8];
  };
  auto ldB = [&](int slot, int z, int fn) -> bf16x8 {
    const int row = wn * 64 + fn * 16 + lr;
    return *(const bf16x8*)&Bs[slot * 12288 + z * 4096 + row * 32 +
                               (lk ^ ((row >> 1) & 3)) * 8];
  };

  // prologue: stage tiles 0,1,2 into slots 0,1,2 (15 loads)
#pragma unroll
  for (int m = 0; m < 3; ++m) {
    stageA(m, m, 0); stageA(m, m, 1);
    stageB(m, m, 0, WqT); stageB(m, m, 1, WkT); stageB(m, m, 2, WvT);
  }
  wait_vmcnt<10>();  // tile 0 landed
  __builtin_amdgcn_s_barrier();

  int slot = 0, slot2 = 2;  // slot = j%3, slot2 = (j+2)%3
  for (int j = 0; j < 64; ++j) {
    bf16x8 af[4], bfr[4];
    // ---- phase 0: z=0 (q)
#pragma unroll
    for (int fm = 0; fm < 4; ++fm) af[fm] = ldA(slot, fm);
#pragma unroll
    for (int fn = 0; fn < 4; ++fn) bfr[fn] = ldB(slot, 0, fn);
    if (j <= 61) { stageA(j + 2, slot2, 0); stageA(j + 2, slot2, 1);
                   stageB(j + 2, slot2, 0, WqT); }
    lgkm0_fence();
    __builtin_amdgcn_s_setprio(1);
#pragma unroll
    for (int fm = 0; fm < 4; ++fm)
#pragma unroll
      for (int fn = 0; fn < 4; ++fn)
        acc[0][fm][fn] = __builtin_amdgcn_mfma_f32_16x16x32_bf16(
            af[fm], bfr[fn], acc[0][fm][fn], 0, 0, 0);
    __builtin_amdgcn_s_setprio(0);
    // ---- phase 1: z=1 (k)
#pragma unroll
    for (int fn = 0; fn < 4; ++fn) bfr[fn] = ldB(slot, 1, fn);
    if (j <= 61) stageB(j + 2, slot2, 1, WkT);
    lgkm0_fence();
    __builtin_amdgcn_s_setprio(1);
#pragma unroll
    for (int fm = 0; fm < 4; ++fm)
#pragma unroll
      for (int fn = 0; fn < 4; ++fn)
        acc[1][fm][fn] = __builtin_amdgcn_mfma_f32_16x16x32_bf16(
            af[fm], bfr[fn], acc[1][fm][fn], 0, 0, 0);
    __builtin_amdgcn_s_setprio(0);
    // ---- phase 2: z=2 (v)
#pragma unroll
    for (int fn = 0; fn < 4; ++fn) bfr[fn] = ldB(slot, 2, fn);
    if (j <= 61) stageB(j + 2, slot2, 2, WvT);
    lgkm0_fence();
    __builtin_amdgcn_s_setprio(1);
#pragma unroll
    for (int fm = 0; fm < 4; ++fm)
#pragma unroll
      for (int fn = 0; fn < 4; ++fn)
        acc[2][fm][fn] = __builtin_amdgcn_mfma_f32_16x16x32_bf16(
            af[fm], bfr[fn], acc[2][fm][fn], 0, 0, 0);
    __builtin_amdgcn_s_setprio(0);
    // ---- end of K-tile: counted drain + single barrier
    if (j <= 61)      wait_vmcnt<5>();
    else if (j == 62) wait_vmcnt<0>();
    __builtin_amdgcn_s_barrier();
    slot = (slot == 2) ? 0 : slot + 1;
    slot2 = (slot2 == 2) ? 0 : slot2 + 1;
  }

  // epilogue: 3 outputs; silu for z=0,1
#pragma unroll
  for (int z = 0; z < 3; ++z) {
    bf16s* outp = (z == 0) ? qb : (z == 1) ? kb : vb;
#pragma unroll
    for (int fm = 0; fm < 4; ++fm) {
      const int row = bm * 256 + wm * 64 + fm * 16 + lk * 4;
#pragma unroll
      for (int fn = 0; fn < 4; ++fn) {
        const int col = bn * 128 + wn * 64 + fn * 16 + lr;
#pragma unroll
        for (int r = 0; r < 4; ++r) {
          float vv = acc[z][fm][fn][r];
          if (z < 2) vv = vv / (1.f + __expf(-vv));  // silu
          outp[(size_t)(row + r) * D_ + col] = f2b(vv);
        }
      }
    }
  }
}

// ======== gemm_out, fz pipeline: BM=256, BN=128, BK=32, 256 blocks =========
__global__ __launch_bounds__(512, 2)
void gemm_out_fz(const bf16s* __restrict__ A, const bf16s* __restrict__ Bt,
                 const float* __restrict__ rs, float* __restrict__ out) {
  const int bn = blockIdx.x & 15, bm = blockIdx.x >> 4;
  __shared__ bf16s As[3 * 256 * 32];   // 48 KB
  __shared__ bf16s Bs[3 * 128 * 32];   // 24 KB
  const int t = threadIdx.x;
  const int w = t >> 6, l = t & 63;
  const int wm = w >> 1, wn = w & 1;
  const int lr = l & 15, lk = l >> 4;
  const int srow = t >> 2;
  const int scs = (t & 3) ^ ((srow >> 1) & 3);

  const size_t abase = (size_t)(bm * 256) * D_;
  const size_t bbase = (size_t)(bn * 128) * D_;

  f32x4 acc[4][4] = {};

  auto stageA = [&](int m, int slot, int p) {
    gload_lds16(&A[abase + (size_t)(p * 128 + srow) * D_ + m * 32 + scs * 8],
                &As[slot * 8192 + p * 4096 + w * 512]);
  };
  auto stageB = [&](int m, int slot) {
    gload_lds16(&Bt[bbase + (size_t)srow * D_ + m * 32 + scs * 8],
                &Bs[slot * 4096 + w * 512]);
  };
  auto ldA = [&](int slot, int fm) -> bf16x8 {
    const int row = wm * 64 + fm * 16 + lr;
    return *(const bf16x8*)&As[slot * 8192 + row * 32 +
                               (lk ^ ((row >> 1) & 3)) * 8];
  };
  auto ldB = [&](int slot, int fn) -> bf16x8 {
    const int row = wn * 64 + fn * 16 + lr;
    return *(const bf16x8*)&Bs[slot * 4096 + row * 32 +
                               (lk ^ ((row >> 1) & 3)) * 8];
  };

#pragma unroll
  for (int m = 0; m < 3; ++m) { stageA(m, m, 0); stageA(m, m, 1); stageB(m, m); }
  wait_vmcnt<6>();  // tile 0 landed
  __builtin_amdgcn_s_barrier();

  int slot = 0, slot2 = 2;
  for (int j = 0; j < 64; ++j) {
    bf16x8 af[4], bfr[4];
#pragma unroll
    for (int fm = 0; fm < 4; ++fm) af[fm] = ldA(slot, fm);
#pragma unroll
    for (int fn = 0; fn < 4; ++fn) bfr[fn] = ldB(slot, fn);
    if (j <= 61) { stageA(j + 2, slot2, 0); stageA(j + 2, slot2, 1);
                   stageB(j + 2, slot2); }
    lgkm0_fence();
    __builtin_amdgcn_s_setprio(1);
#pragma unroll
    for (int fm = 0; fm < 4; ++fm)
#pragma unroll
      for (int fn = 0; fn < 4; ++fn)
        acc[fm][fn] = __builtin_amdgcn_mfma_f32_16x16x32_bf16(
            af[fm], bfr[fn], acc[fm][fn], 0, 0, 0);
    __builtin_amdgcn_s_setprio(0);
    if (j <= 61)      wait_vmcnt<3>();
    else if (j == 62) wait_vmcnt<0>();
    __builtin_amdgcn_s_barrier();
    slot = (slot == 2) ? 0 : slot + 1;
    slot2 = (slot2 == 2) ? 0 : slot2 + 1;
  }

#pragma unroll
  for (int fm = 0; fm < 4; ++fm) {
    const int row = bm * 256 + wm * 64 + fm * 16 + lk * 4;
#pragma unroll
    for (int fn = 0; fn < 4; ++fn) {
      const int col = bn * 128 + wn * 64 + fn * 16 + lr;
#pragma unroll
      for (int r = 0; r < 4; ++r)
        out[(size_t)(row + r) * D_ + col] = acc[fm][fn][r] * rs[row + r];
    }
  }
}

// ============ chunked linear attention, 3-pass parallel decomposition =======
__global__ __launch_bounds__(256)
void chunk_state(const bf16s* __restrict__ k, const bf16s* __restrict__ v,
                 const float* __restrict__ ldp, bf16s* __restrict__ Mbuf,
                 float* __restrict__ totb) {
  const int c = blockIdx.x, bh = blockIdx.y;
  const int b = bh >> 4, h = bh & 15;
  const int t = threadIdx.x;
  const int w = t >> 6, l = t & 63;
  const int lr = l & 15, lk = l >> 4;

  __shared__ bf16s Kt[64 * 128];
  __shared__ bf16s Vn[64 * 128];
  __shared__ bf16s KdT[128 * 64];
  __shared__ bf16s VtT[128 * 64];
  __shared__ float cumS[64];
  char* cKt = (char*)Kt; char* cVn = (char*)Vn;
  char* cKdT = (char*)KdT; char* cVtT = (char*)VtT;

  const size_t grow0 = (size_t)b * NSEQ_ + c * 64;
#pragma unroll
  for (int j = 0; j < 4; ++j) {
    const int lrow = w * 16 + j * 4 + (l >> 4);
    const int ck = (l & 15) ^ (lrow & 7);
    const size_t goff = (grow0 + lrow) * D_ + h * E_ + ck * 8;
    const int lbase = (w * 16 + j * 4) * 128;
    gload_lds16(&k[goff], &Kt[lbase]);
    gload_lds16(&v[goff], &Vn[lbase]);
  }
  if (w == 0) {
    float val = ldp[(grow0 + l) * H_ + h];
#pragma unroll
    for (int off = 1; off < 64; off <<= 1) {
      float pv = __shfl_up(val, off);
      if (l >= off) val += pv;
    }
    cumS[l] = val;
  }
  __syncthreads();
  const float tot = cumS[63];
  if (t == 0) totb[bh * NCH_ + c] = tot;

#pragma unroll
  for (int it = 0; it < 4; ++it) {
    const int task = t + it * 256;
    const int i = task >> 4, cx = task & 15;
    const int sb = i * 256 + ((cx * 16) ^ ((i & 7) << 4));
    bf16x8 vv = *(const bf16x8*)(cVn + sb);
    bf16x8 kk8 = *(const bf16x8*)(cKt + sb);
    const float sE = __expf(tot - cumS[i]);
#pragma unroll
    for (int jj = 0; jj < 8; ++jj) {
      const int e = cx * 8 + jj;
      const int db = e * 128 + ((i * 2) ^ ((e & 7) << 4));
      *(bf16s*)(cVtT + db) = vv[jj];
      *(bf16s*)(cKdT + db) = f2b(b2f(kk8[jj]) * sE);
    }
  }
  __syncthreads();

  const int wm = w >> 1, wn = w & 1;
  f32x4 acc[4][4] = {};
#pragma unroll
  for (int kk2 = 0; kk2 < 2; ++kk2) {
    const int cb = (kk2 * 32 + lk * 8) * 2;
    bf16x8 af[4], bfr[4];
#pragma unroll
    for (int tm = 0; tm < 4; ++tm) {
      const int fr = wm * 64 + tm * 16 + lr;
      af[tm] = *(const bf16x8*)(cVtT + fr * 128 + (cb ^ ((fr & 7) << 4)));
    }
#pragma unroll
    for (int tn = 0; tn < 4; ++tn) {
      const int er = wn * 64 + tn * 16 + lr;
      bfr[tn] = *(const bf16x8*)(cKdT + er * 128 + (cb ^ ((er & 7) << 4)));
    }
#pragma unroll
    for (int tm = 0; tm < 4; ++tm)
#pragma unroll
      for (int tn = 0; tn < 4; ++tn)
        acc[tm][tn] = __builtin_amdgcn_mfma_f32_16x16x32_bf16(
            af[tm], bfr[tn], acc[tm][tn], 0, 0, 0);
  }
  const size_t mb = (size_t)(bh * NCH_ + c) * 128 * 128;
#pragma unroll
  for (int tm = 0; tm < 4; ++tm) {
#pragma unroll
    for (int tn = 0; tn < 4; ++tn) {
#pragma unroll
      for (int r = 0; r < 4; ++r) {
        const int f = wm * 64 + tm * 16 + lk * 4 + r;
        const int e = wn * 64 + tn * 16 + lr;
        Mbuf[mb + f * 128 + e] = f2b(acc[tm][tn][r]);
      }
    }
  }
}

__global__ __launch_bounds__(256)
void state_scan(const bf16s* __restrict__ Mbuf, const float* __restrict__ totb,
                bf16s* __restrict__ Sbuf) {
  const int sl = blockIdx.x;
  const int bh = blockIdx.y;
  const int t = threadIdx.x;
  const int fr = sl * 16 + (t >> 4);
  const int e0 = (t & 15) * 8;
  const size_t base = ((size_t)(bh * NCH_) * 128 + fr) * 128 + e0;
  const size_t cstride = 128 * 128;
  __shared__ float tots[NCH_];
  if (t < NCH_) tots[t] = totb[bh * NCH_ + t];
  __syncthreads();
  float acc[8] = {};
  bf16x8 m0 = *(const bf16x8*)&Mbuf[base + 0 * cstride];
  bf16x8 m1 = *(const bf16x8*)&Mbuf[base + 1 * cstride];
  bf16x8 m2 = *(const bf16x8*)&Mbuf[base + 2 * cstride];
  bf16x8 m3 = *(const bf16x8*)&Mbuf[base + 3 * cstride];
#pragma unroll
  for (int c = 0; c < NCH_; ++c) {
    bf16x8 sv;
#pragma unroll
    for (int j = 0; j < 8; ++j) sv[j] = f2b(acc[j]);
    *(bf16x8*)&Sbuf[base + (size_t)c * cstride] = sv;
    const bf16x8 mc = ((c & 3) == 0) ? m0 : ((c & 3) == 1) ? m1
                     : ((c & 3) == 2) ? m2 : m3;
    const float dt = __expf(tots[c]);
#pragma unroll
    for (int j = 0; j < 8; ++j) acc[j] = acc[j] * dt + b2f(mc[j]);
    if (c + 4 < NCH_) {
      const bf16x8 mn = *(const bf16x8*)&Mbuf[base + (size_t)(c + 4) * cstride];
      if ((c & 3) == 0) m0 = mn;
      else if ((c & 3) == 1) m1 = mn;
      else if ((c & 3) == 2) m2 = mn;
      else m3 = mn;
    }
  }
}

__global__ __launch_bounds__(256)
void attn_out(const bf16s* __restrict__ q, const bf16s* __restrict__ k,
              const bf16s* __restrict__ v, const float* __restrict__ ldp,
              const bf16s* __restrict__ Sbuf, bf16s* __restrict__ o) {
  const int c = blockIdx.x, bh = blockIdx.y;
  const int b = bh >> 4, h = bh & 15;
  const int t = threadIdx.x;
  const int w = t >> 6, l = t & 63;
  const int lr = l & 15, lk = l >> 4;

  __shared__ bf16s Qt[64 * 128];
  __shared__ bf16s Kt[64 * 128];
  __shared__ bf16s Vn[64 * 128];
  __shared__ bf16s VtT[128 * 64];
  __shared__ bf16s Pm[64 * 64];
  __shared__ float cumS[64];
  char* cQt = (char*)Qt; char* cKt = (char*)Kt; char* cVn = (char*)Vn;
  char* cVtT = (char*)VtT; char* cPm = (char*)Pm;

  const size_t grow0 = (size_t)b * NSEQ_ + c * 64;
  const size_t sbase = (size_t)(bh * NCH_ + c) * 128 * 128;
  const bf16x8* Sp = (const bf16x8*)&Sbuf[sbase];
#pragma unroll
  for (int j = 0; j < 4; ++j) {
    const int lrow = w * 16 + j * 4 + (l >> 4);
    const int ck = (l & 15) ^ (lrow & 7);
    const size_t goff = (grow0 + lrow) * D_ + h * E_ + ck * 8;
    const int lbase = (w * 16 + j * 4) * 128;
    gload_lds16(&q[goff], &Qt[lbase]);
    gload_lds16(&k[goff], &Kt[lbase]);
    gload_lds16(&v[goff], &Vn[lbase]);
  }
  if (w == 0) {
    float val = ldp[(grow0 + l) * H_ + h];
#pragma unroll
    for (int off = 1; off < 64; off <<= 1) {
      float pv = __shfl_up(val, off);
      if (l >= off) val += pv;
    }
    cumS[l] = val;
  }
  __syncthreads();

#pragma unroll
  for (int it = 0; it < 4; ++it) {
    const int task = t + it * 256;
    const int i = task >> 4, cx = task & 15;
    const int sb = i * 256 + ((cx * 16) ^ ((i & 7) << 4));
    bf16x8 vv = *(const bf16x8*)(cVn + sb);
#pragma unroll
    for (int jj = 0; jj < 8; ++jj) {
      const int e = cx * 8 + jj;
      const int db = e * 128 + ((i * 2) ^ ((e & 7) << 4));
      *(bf16s*)(cVtT + db) = vv[jj];
    }
  }

  f32x4 accs[4] = {};
  f32x4 acco[8] = {};
#pragma unroll
  for (int kk = 0; kk < 4; ++kk) {
    const int cb = (kk * 32 + lk * 8) * 2;
    const int ar = w * 16 + lr;
    bf16x8 aq = *(const bf16x8*)(cQt + ar * 256 + (cb ^ ((ar & 7) << 4)));
#pragma unroll
    for (int tn = 0; tn < 4; ++tn) {
      const int br = tn * 16 + lr;
      bf16x8 bk = *(const bf16x8*)(cKt + br * 256 + (cb ^ ((br & 7) << 4)));
      accs[tn] = __builtin_amdgcn_mfma_f32_16x16x32_bf16(aq, bk, accs[tn], 0, 0, 0);
    }
#pragma unroll
    for (int tf = 0; tf < 8; ++tf) {
      bf16x8 bs = Sp[(tf * 16 + lr) * 16 + kk * 4 + lk];
      acco[tf] = __builtin_amdgcn_mfma_f32_16x16x32_bf16(aq, bs, acco[tf], 0, 0, 0);
    }
  }
#pragma unroll
  for (int r = 0; r < 4; ++r) {
    const float gI = __expf(cumS[w * 16 + lk * 4 + r]);
#pragma unroll
    for (int tf = 0; tf < 8; ++tf) acco[tf][r] *= gI;
  }
#pragma unroll
  for (int tn = 0; tn < 4; ++tn) {
    const int j = tn * 16 + lr;
    const float cj = cumS[j];
#pragma unroll
    for (int r = 0; r < 4; ++r) {
      const int i = w * 16 + lk * 4 + r;
      const float sv = (j <= i) ? accs[tn][r] * __expf(cumS[i] - cj) : 0.f;
      *(bf16s*)(cPm + i * 128 + ((j * 2) ^ ((i & 7) << 4))) = f2b(sv);
    }
  }
  __syncthreads();

#pragma unroll
  for (int kk2 = 0; kk2 < 2; ++kk2) {
    const int cb = (kk2 * 32 + lk * 8) * 2;
    const int pr = w * 16 + lr;
    bf16x8 ap = *(const bf16x8*)(cPm + pr * 128 + (cb ^ ((pr & 7) << 4)));
#pragma unroll
    for (int tf = 0; tf < 8; ++tf) {
      const int fr = tf * 16 + lr;
      bf16x8 bv = *(const bf16x8*)(cVtT + fr * 128 + (cb ^ ((fr & 7) << 4)));
      acco[tf] = __builtin_amdgcn_mfma_f32_16x16x32_bf16(ap, bv, acco[tf], 0, 0, 0);
    }
  }
#pragma unroll
  for (int tf = 0; tf < 8; ++tf) {
#pragma unroll
    for (int r = 0; r < 4; ++r) {
      const int i = w * 16 + lk * 4 + r;
      o[(grow0 + i) * D_ + h * E_ + tf * 16 + lr] = f2b(acco[tf][r]);
    }
  }
}

// -------- RMS scale only: s[tok] = rsqrt(mean(o^2)+eps) --------------------
__global__ __launch_bounds__(256)
void rms_scale(const bf16s* __restrict__ o, float* __restrict__ sout) {
  const int tok = blockIdx.x;
  const int t = threadIdx.x;
  bf16x8 vv = *(const bf16x8*)&o[(size_t)tok * D_ + t * 8];
  float s = 0.f;
#pragma unroll
  for (int j = 0; j < 8; ++j) { const float f = b2f(vv[j]); s += f * f; }
#pragma unroll
  for (int off2 = 32; off2 > 0; off2 >>= 1) s += __shfl_down(s, off2);
  __shared__ float wsum[4];
  if ((t & 63) == 0) wsum[t >> 6] = s;
  __syncthreads();
  if (t == 0)
    sout[tok] = rsqrtf((wsum[0] + wsum[1] + wsum[2] + wsum[3]) * (1.f / D_) +
                       1e-6f);
}

extern "C" void kernel_launch(void* const* d_in, const int* in_sizes, int n_in,
                              void* d_out, int out_size, void* d_ws,
                              size_t ws_size, hipStream_t stream) {
  (void)in_sizes; (void)n_in; (void)out_size;
  const float* x  = (const float*)d_in[0];
  const float* Wq = (const float*)d_in[1];
  const float* Wk = (const float*)d_in[2];
  const float* Wv = (const float*)d_in[3];
  const float* Wf = (const float*)d_in[4];
  const float* Wo = (const float*)d_in[5];
  const float* nw = (const float*)d_in[6];
  float* out = (float*)d_out;

  char* ws = (char*)d_ws;
  const size_t MB = 1024 * 1024;
  bf16s* xb   = (bf16s*)(ws + 0);
  bf16s* WqT  = (bf16s*)(ws + 16 * MB);
  bf16s* WkT  = (bf16s*)(ws + 24 * MB);
  bf16s* WvT  = (bf16s*)(ws + 32 * MB);
  bf16s* Sbuf = (bf16s*)(ws + 0);        // alias: live after gemm_qkv
  float* totb = (float*)(ws + 32 * MB);  // alias: live after gemm_qkv
  bf16s* WoT  = (bf16s*)(ws + 40 * MB);
  bf16s* qb   = (bf16s*)(ws + 48 * MB);
  bf16s* kb   = (bf16s*)(ws + 64 * MB);
  bf16s* vb   = (bf16s*)(ws + 80 * MB);
  bf16s* ob   = (bf16s*)(ws + 96 * MB);
  bf16s* Mbuf = (bf16s*)(ws + 112 * MB);
  float* ldb  = (float*)(ws + 144 * MB);
  float* rsb  = (float*)(ws + 145 * MB);
  if (146 * MB > ws_size) return;

  cvt_bf16<<<NTOK_ * D_ / 8 / 256, 256, 0, stream>>>(x, xb);
  transpose_w<<<dim3(32, 32, 4), 256, 0, stream>>>(Wq, Wk, Wv, Wo, nw, WqT,
                                                   WkT, WvT, WoT);
  ld_gemm<<<NTOK_ / 16, 256, 0, stream>>>(x, Wf, ldb);
  gemm_qkv_fz<<<256, 512, 0, stream>>>(xb, WqT, WkT, WvT, qb, kb, vb);
  chunk_state<<<dim3(NCH_, NB_ * H_), 256, 0, stream>>>(kb, vb, ldb, Mbuf, totb);
  state_scan<<<dim3(8, NB_ * H_), 256, 0, stream>>>(Mbuf, totb, Sbuf);
  attn_out<<<dim3(NCH_, NB_ * H_), 256, 0, stream>>>(qb, kb, vb, ldb, Sbuf, ob);
  rms_scale<<<NTOK_, 256, 0, stream>>>(ob, rsb);
  gemm_out_fz<<<256, 512, 0, stream>>>(ob, WoT, rsb, out);
}